// Round 8
// baseline (370.398 us; speedup 1.0000x reference)
//
#include <hip/hip_runtime.h>
#include <math.h>

#define NIN 12
#define HID 256
#define NOUT 12
#define BM 64
#define THREADS 512
#define NBLK (262144 / BM)

typedef _Float16 f16;
typedef f16 f16x8 __attribute__((ext_vector_type(8)));
typedef float f32x4 __attribute__((ext_vector_type(4)));

__device__ __forceinline__ void gll16(const void* g, void* l) {
    __builtin_amdgcn_global_load_lds(
        (const __attribute__((address_space(1))) unsigned int*)g,
        (__attribute__((address_space(3))) unsigned int*)l, 16, 0, 0);
}

// d_ws: W2 fp16 splits in MFMA-B fragment order:
// half index = (((s*2 + spl)*16 + ct)*64 + l)*8 + j
// where k = 32s + 8*(l>>4) + j, col = 16*ct + (l&15). Total 131072 halfs = 256 KB.
__global__ void prep_w2(const float* __restrict__ W2, f16* __restrict__ w2p) {
    const int e = (blockIdx.x * 256 + threadIdx.x) * 4;
    const int k = e >> 8, col0 = e & 255;
    const float4 w = *(const float4*)(W2 + k * HID + col0);
    const int s = k >> 5, lgw = (k >> 3) & 3, j = k & 7;
    #pragma unroll
    for (int q = 0; q < 4; ++q) {
        const float v = ((const float*)&w)[q];
        const f16 hi = (f16)v;
        const f16 lo = (f16)(v - (float)hi);
        const int c = col0 + q, ct = c >> 4, cc = c & 15, l = (lgw << 4) | cc;
        w2p[(size_t)(((s*2 + 0)*16 + ct)*64 + l)*8 + j] = hi;
        w2p[(size_t)(((s*2 + 1)*16 + ct)*64 + l)*8 + j] = lo;
    }
}

// LDS map (72704 B total):
//   [0, 32768)      Bl0 (B chunk buffer A); post-GEMM overlay: W3s [0,12288), h1f @12288, h2f @13312
//   [32768, 65536)  Bl1 (B chunk buffer B)
//   [65536, 66560)  b2s (256 f32)
//   [66560, 72704)  psum [2 wc][64 r][12 jj]; recompute-phase psum[12][16] reuses it
__global__ __launch_bounds__(THREADS, 4)
void mlp_main(const float* __restrict__ inp, const float* __restrict__ W1,
              const float* __restrict__ b1, const float* __restrict__ W2,
              const float* __restrict__ b2, const float* __restrict__ W3,
              const float* __restrict__ b3, const f16* __restrict__ w2p,
              float* __restrict__ out)
{
    __shared__ __align__(16) unsigned char smem[72704];
    __shared__ int nflag;
    __shared__ int flaglist[16];

    float* b2s  = (float*)(smem + 65536);
    float* psum = (float*)(smem + 66560);
    float* W3s  = (float*)smem;              // valid only after the GEMM loop
    float* h1f  = (float*)(smem + 12288);
    float* h2f  = (float*)(smem + 13312);

    const int t    = threadIdx.x;
    const int lane = t & 63;
    const int wid  = t >> 6;      // 0..7
    const int wr   = wid & 3;     // row-group: rows 16*wr .. 16*wr+15
    const int wc   = wid >> 2;    // col-half: cols 128*wc .. 128*wc+127
    const int cl   = lane & 15;
    const int lg   = lane >> 4;
    const int row0 = blockIdx.x * BM;

    if (t == 0) nflag = 0;

    // ---- prologue: stage b2 (1 KB) + B chunk 0 (32 KB) ----
    if (t < 64) gll16((const char*)b2 + t*16, smem + 65536 + t*16);
    {
        const char* src = (const char*)w2p;
        #pragma unroll
        for (int i = 0; i < 4; ++i)
            gll16(src + (i*THREADS + t)*16, smem + (i*THREADS + t)*16);
    }

    // ---- this lane's input row (A-frag: lane (cl,lg) owns row 16*wr+cl) ----
    const int myrow = row0 + wr*16 + cl;
    float xin[12];
    {
        const f32x4* ip = (const f32x4*)(inp + (size_t)myrow * NIN);
        const f32x4 a = ip[0], b = ip[1], c = ip[2];
        xin[0]=a.x; xin[1]=a.y; xin[2]=a.z; xin[3]=a.w;
        xin[4]=b.x; xin[5]=b.y; xin[6]=b.z; xin[7]=b.w;
        xin[8]=c.x; xin[9]=c.y; xin[10]=c.z; xin[11]=c.w;
    }

    // ---- GEMM2: double-buffered B staging, one barrier per chunk ----
    f32x4 acc[8];
    {
        const f32x4 zero = {0.f, 0.f, 0.f, 0.f};
        #pragma unroll
        for (int ct = 0; ct < 8; ++ct) acc[ct] = zero;
    }
    #pragma unroll
    for (int s = 0; s < 8; ++s) {
        // Layer 1 for this chunk (register-only; covers chunk-s load latency)
        const int k0 = 32*s + 8*lg;
        float a0[8];
        {
            const f32x4 bb0 = *(const f32x4*)(b1 + k0);
            const f32x4 bb1 = *(const f32x4*)(b1 + k0 + 4);
            a0[0]=bb0.x; a0[1]=bb0.y; a0[2]=bb0.z; a0[3]=bb0.w;
            a0[4]=bb1.x; a0[5]=bb1.y; a0[6]=bb1.z; a0[7]=bb1.w;
        }
        #pragma unroll
        for (int m = 0; m < 12; ++m) {
            const float xm = xin[m];
            const f32x4 w0 = *(const f32x4*)(W1 + m*HID + k0);
            const f32x4 w1 = *(const f32x4*)(W1 + m*HID + k0 + 4);
            a0[0] = fmaf(xm, w0.x, a0[0]); a0[1] = fmaf(xm, w0.y, a0[1]);
            a0[2] = fmaf(xm, w0.z, a0[2]); a0[3] = fmaf(xm, w0.w, a0[3]);
            a0[4] = fmaf(xm, w1.x, a0[4]); a0[5] = fmaf(xm, w1.y, a0[5]);
            a0[6] = fmaf(xm, w1.z, a0[6]); a0[7] = fmaf(xm, w1.w, a0[7]);
        }
        f16x8 ahi, alo;
        #pragma unroll
        for (int j = 0; j < 8; ++j) {
            const float h = fmaxf(a0[j], 0.f);
            const f16 hi = (f16)h;
            ahi[j] = hi;
            alo[j] = (f16)(h - (float)hi);
        }

        // own chunk-s loads were issued a full iteration ago -> latency covered
        asm volatile("s_waitcnt vmcnt(0)" ::: "memory");
        __syncthreads();   // all waves' chunk-s writes landed; buf[(s+1)&1] free

        if (s < 7) {       // issue chunk s+1 while we do MFMA on chunk s
            const char* src = (const char*)w2p + (size_t)(s+1) * 32768;
            char* dst = (char*)smem + ((s+1)&1) * 32768;
            #pragma unroll
            for (int i = 0; i < 4; ++i)
                gll16(src + (i*THREADS + t)*16, dst + (i*THREADS + t)*16);
        }

        const char* bufr = (const char*)smem + (s&1) * 32768;
        #pragma unroll
        for (int ct = 0; ct < 8; ++ct) {
            const int gct = wc*8 + ct;
            const f16x8 bhi = *(const f16x8*)(bufr + (size_t)(( 0 + gct)*64 + lane)*16);
            const f16x8 blo = *(const f16x8*)(bufr + (size_t)((16 + gct)*64 + lane)*16);
            acc[ct] = __builtin_amdgcn_mfma_f32_16x16x32_f16(ahi, bhi, acc[ct], 0, 0, 0);
            acc[ct] = __builtin_amdgcn_mfma_f32_16x16x32_f16(ahi, blo, acc[ct], 0, 0, 0);
            acc[ct] = __builtin_amdgcn_mfma_f32_16x16x32_f16(alo, bhi, acc[ct], 0, 0, 0);
        }
    }

    // ---- stage W3 into the (dead) Bl0 region ----
    __syncthreads();   // all MFMA LDS reads done
    {
        const char* w3c = (const char*)W3;
        gll16(w3c + t*16, smem + t*16);                          // 8 KB
        if (t < 256) gll16(w3c + 8192 + t*16, smem + 8192 + t*16);  // 4 KB
    }
    asm volatile("s_waitcnt vmcnt(0)" ::: "memory");
    __syncthreads();

    // ---- Layer 3 (exact fp32), jj split 8/4, butterfly over cl ----
    float x[12];   // meaningful for cl<4 after butterflies
    {
        float part[4][8];
        #pragma unroll
        for (int q = 0; q < 4; ++q)
            #pragma unroll
            for (int jj = 0; jj < 8; ++jj) part[q][jj] = 0.f;

        #pragma unroll
        for (int ct = 0; ct < 8; ++ct) {
            const int col = (wc*8 + ct)*16 + cl;
            const float bv = b2s[col];
            const f32x4 w3a = *(const f32x4*)(W3s + col*12);
            const f32x4 w3b = *(const f32x4*)(W3s + col*12 + 4);
            #pragma unroll
            for (int q = 0; q < 4; ++q) {
                const float h2 = fmaxf(acc[ct][q] + bv, 0.f);
                part[q][0] = fmaf(h2, w3a.x, part[q][0]);
                part[q][1] = fmaf(h2, w3a.y, part[q][1]);
                part[q][2] = fmaf(h2, w3a.z, part[q][2]);
                part[q][3] = fmaf(h2, w3a.w, part[q][3]);
                part[q][4] = fmaf(h2, w3b.x, part[q][4]);
                part[q][5] = fmaf(h2, w3b.y, part[q][5]);
                part[q][6] = fmaf(h2, w3b.z, part[q][6]);
                part[q][7] = fmaf(h2, w3b.w, part[q][7]);
            }
        }
        #pragma unroll
        for (int m = 1; m < 16; m <<= 1)
            #pragma unroll
            for (int q = 0; q < 4; ++q)
                #pragma unroll
                for (int jj = 0; jj < 8; ++jj)
                    part[q][jj] += __shfl_xor(part[q][jj], m);
        if (cl < 4) {
            #pragma unroll
            for (int jj = 0; jj < 8; ++jj) x[jj] = part[cl][jj];
        }
    }
    {
        float part[4][4];
        #pragma unroll
        for (int q = 0; q < 4; ++q)
            #pragma unroll
            for (int jj = 0; jj < 4; ++jj) part[q][jj] = 0.f;

        #pragma unroll
        for (int ct = 0; ct < 8; ++ct) {
            const int col = (wc*8 + ct)*16 + cl;
            const float bv = b2s[col];
            const f32x4 w3c = *(const f32x4*)(W3s + col*12 + 8);
            #pragma unroll
            for (int q = 0; q < 4; ++q) {
                const float h2 = fmaxf(acc[ct][q] + bv, 0.f);
                part[q][0] = fmaf(h2, w3c.x, part[q][0]);
                part[q][1] = fmaf(h2, w3c.y, part[q][1]);
                part[q][2] = fmaf(h2, w3c.z, part[q][2]);
                part[q][3] = fmaf(h2, w3c.w, part[q][3]);
            }
        }
        #pragma unroll
        for (int m = 1; m < 16; m <<= 1)
            #pragma unroll
            for (int q = 0; q < 4; ++q)
                #pragma unroll
                for (int jj = 0; jj < 4; ++jj)
                    part[q][jj] += __shfl_xor(part[q][jj], m);
        if (cl < 4) {
            #pragma unroll
            for (int jj = 0; jj < 4; ++jj) x[8 + jj] = part[cl][jj];
        }
    }

    // lanes cl<4 write this col-half's partial for row 16*wr + 4*lg + cl
    if (cl < 4) {
        const int R = wr*16 + 4*lg + cl;
        float* p = psum + (size_t)(wc*BM + R) * 12;
        #pragma unroll
        for (int jj = 0; jj < 12; ++jj) p[jj] = x[jj];
    }
    __syncthreads();

    // ---- epilogue (exact fp32): thread t<64 owns row t ----
    if (t < BM) {
        const int r = t;
        const int grow = row0 + r;
        float xr_[12];
        #pragma unroll
        for (int jj = 0; jj < 12; ++jj)
            xr_[jj] = psum[r*12 + jj] + psum[(BM + r)*12 + jj] + b3[jj];

        const f32x4* ip = (const f32x4*)(inp + (size_t)grow * NIN);
        const f32x4 iA = ip[0], iB = ip[1], iC = ip[2];
        const float in0=iA.x, in1=iA.y, in2=iA.z, in6=iB.z, in7=iB.w, in8=iC.x, in9=iC.y;

        const float pos0=tanhf(xr_[0]), pos1=tanhf(xr_[1]), pos2=tanhf(xr_[2]);
        const float vel0=tanhf(xr_[3]), vel1=tanhf(xr_[4]), vel2=tanhf(xr_[5]);
        const float pts = 1.f/(1.f+expf(-xr_[6]));
        const float cl0=tanhf(xr_[7]), cl1=tanhf(xr_[8]), cl2=tanhf(xr_[9]);
        const float sn0=tanhf(xr_[10]), sn1=tanhf(xr_[11]);

        const float dist = sqrtf(pos0*pos0 + pos1*pos1 + pos2*pos2);
        float pc0=pos0, pc1=pos1, pc2=pos2;
        if (dist > 1.0f) { pc0 = pos0/dist; pc1 = pos1/dist; pc2 = pos2/dist; }

        const float prev = in6;
        float pts_c = (pts > 1.0f) ? 1.0f : pts;
        pts_c = (pts < prev) ? prev : pts_c;

        const float de0 = cl0-in7, de1 = cl1-in8, de2 = cl2-in9;
        const float dp0 = in0-in7, dp1 = in1-in8, dp2 = in2-in9;
        const float dpn = sqrtf(dp0*dp0 + dp1*dp1 + dp2*dp2);
        const float nd0 = dp0/dpn, nd1 = dp1/dpn, nd2 = dp2/dpn;
        const float dd  = de0*dp0 + de1*dp1 + de2*dp2;
        float off0, off1, off2;
        if (dd > 0.0f) { off0 = cl0-nd0; off1 = cl1-nd1; off2 = cl2-nd2; }
        else           { off0 = cl0;     off1 = cl1;     off2 = cl2;     }
        const float cdist = sqrtf(off0*off0 + off1*off1 + off2*off2);
        float cc0, cc1, cc2;
        if (cdist > 1.0f) { cc0 = off0/cdist; cc1 = off1/cdist; cc2 = off2/cdist; }
        else              { cc0 = cl0;        cc1 = cl1;        cc2 = cl2;        }

        const float snn = sqrtf(sn0*sn0 + sn1*sn1);
        const float sc0 = sn0/snn, sc1 = sn1/snn;

        // guard: branch decisions within fp16-split error margin -> exact recompute
        if (fabsf(dd) < 2e-4f || (dd > 0.f && fabsf(cdist - 1.f) < 2e-4f)) {
            const int slot = atomicAdd(&nflag, 1);
            if (slot < 16) flaglist[slot] = r;
        }

        f32x4* dst = (f32x4*)(out + (size_t)grow * NOUT);
        f32x4 o0 = {pc0, pc1, pc2, vel0};
        f32x4 o1 = {vel1, vel2, pts_c, cc0};
        f32x4 o2 = {cc1, cc2, sc0, sc1};
        dst[0] = o0; dst[1] = o1; dst[2] = o2;
    }
    __syncthreads();

    // ---- exact fp32 recompute of flagged rows (rare across whole GPU) ----
    const int nf = (nflag < 16) ? nflag : 16;
    for (int f = 0; f < nf; ++f) {
        const int grow = row0 + flaglist[f];
        if (t < HID) {
            float a = b1[t];
            const float* xr = inp + (size_t)grow * NIN;
            #pragma unroll
            for (int m = 0; m < 12; ++m) a = fmaf(xr[m], W1[m*HID + t], a);
            h1f[t] = fmaxf(a, 0.f);
        }
        __syncthreads();
        if (t < HID) {
            float a = b2[t];
            for (int k = 0; k < HID; ++k) a = fmaf(h1f[k], W2[k*HID + t], a);
            h2f[t] = fmaxf(a, 0.f);
        }
        __syncthreads();
        if (t < 12*16) {
            const int jj = t >> 4, seg = t & 15;
            float a = 0.f;
            #pragma unroll
            for (int u = 0; u < 16; ++u) a = fmaf(h2f[seg*16 + u], W3[(seg*16 + u)*NOUT + jj], a);
            psum[jj*16 + seg] = a;
        }
        __syncthreads();
        if (t == 0) {
            float xx[12];
            #pragma unroll
            for (int jj = 0; jj < 12; ++jj) {
                float sacc = b3[jj];
                for (int g = 0; g < 16; ++g) sacc += psum[jj*16 + g];
                xx[jj] = sacc;
            }
            const float* xr = inp + (size_t)grow * NIN;
            const float in0=xr[0], in1=xr[1], in2=xr[2], in6=xr[6], in7=xr[7], in8=xr[8], in9=xr[9];
            const float pos0=tanhf(xx[0]), pos1=tanhf(xx[1]), pos2=tanhf(xx[2]);
            const float vel0=tanhf(xx[3]), vel1=tanhf(xx[4]), vel2=tanhf(xx[5]);
            const float pts = 1.f/(1.f+expf(-xx[6]));
            const float cl0=tanhf(xx[7]), cl1=tanhf(xx[8]), cl2=tanhf(xx[9]);
            const float sn0=tanhf(xx[10]), sn1=tanhf(xx[11]);
            const float dist = sqrtf(pos0*pos0 + pos1*pos1 + pos2*pos2);
            float pc0=pos0, pc1=pos1, pc2=pos2;
            if (dist > 1.0f) { pc0 = pos0/dist; pc1 = pos1/dist; pc2 = pos2/dist; }
            const float prev = in6;
            float pts_c = (pts > 1.0f) ? 1.0f : pts;
            pts_c = (pts < prev) ? prev : pts_c;
            const float de0 = cl0-in7, de1 = cl1-in8, de2 = cl2-in9;
            const float dp0 = in0-in7, dp1 = in1-in8, dp2 = in2-in9;
            const float dpn = sqrtf(dp0*dp0 + dp1*dp1 + dp2*dp2);
            const float nd0 = dp0/dpn, nd1 = dp1/dpn, nd2 = dp2/dpn;
            const float dd  = de0*dp0 + de1*dp1 + de2*dp2;
            float off0, off1, off2;
            if (dd > 0.0f) { off0 = cl0-nd0; off1 = cl1-nd1; off2 = cl2-nd2; }
            else           { off0 = cl0;     off1 = cl1;     off2 = cl2;     }
            const float cdist = sqrtf(off0*off0 + off1*off1 + off2*off2);
            float cc0, cc1, cc2;
            if (cdist > 1.0f) { cc0 = off0/cdist; cc1 = off1/cdist; cc2 = off2/cdist; }
            else              { cc0 = cl0;        cc1 = cl1;        cc2 = cl2;        }
            const float snn = sqrtf(sn0*sn0 + sn1*sn1);
            const float sc0 = sn0/snn, sc1 = sn1/snn;
            float* dst = out + (size_t)grow * NOUT;
            dst[0]=pc0; dst[1]=pc1; dst[2]=pc2; dst[3]=vel0; dst[4]=vel1; dst[5]=vel2;
            dst[6]=pts_c; dst[7]=cc0; dst[8]=cc1; dst[9]=cc2; dst[10]=sc0; dst[11]=sc1;
        }
        __syncthreads();
    }
}

extern "C" void kernel_launch(void* const* d_in, const int* in_sizes, int n_in,
                              void* d_out, int out_size, void* d_ws, size_t ws_size,
                              hipStream_t stream) {
    const float* inp = (const float*)d_in[0];
    const float* W1  = (const float*)d_in[1];
    const float* b1  = (const float*)d_in[2];
    const float* W2  = (const float*)d_in[3];
    const float* b2  = (const float*)d_in[4];
    const float* W3  = (const float*)d_in[5];
    const float* b3  = (const float*)d_in[6];
    float* out = (float*)d_out;
    f16* w2p = (f16*)d_ws;   // needs 256 KB

    hipLaunchKernelGGL(prep_w2, dim3(64), dim3(256), 0, stream, W2, w2p);
    hipLaunchKernelGGL(mlp_main, dim3(NBLK), dim3(THREADS), 0, stream,
                       inp, W1, b1, W2, b2, W3, b3, (const f16*)w2p, out);
}

// Round 9
// 287.465 us; speedup vs baseline: 1.2885x; 1.2885x over previous
//
#include <hip/hip_runtime.h>
#include <math.h>

#define NIN 12
#define HID 256
#define NOUT 12
#define BM 64
#define NBLK (262144 / BM)

typedef _Float16 f16;
typedef f16 f16x8 __attribute__((ext_vector_type(8)));
typedef float f32x4 __attribute__((ext_vector_type(4)));

__device__ __forceinline__ void gll16(const void* g, void* l) {
    __builtin_amdgcn_global_load_lds(
        (const __attribute__((address_space(1))) unsigned int*)g,
        (__attribute__((address_space(3))) unsigned int*)l, 16, 0, 0);
}

// d_ws: W2 as fp16 (hi only) in MFMA-B fragment order:
// half index = ((s*16 + ct)*64 + l)*8 + j
// where k = 32s + 8*(l>>4) + j, col = 16*ct + (l&15). Total 65536 halfs = 128 KB.
__global__ void prep_w2(const float* __restrict__ W2, f16* __restrict__ w2p) {
    const int e = (blockIdx.x * 256 + threadIdx.x) * 4;
    const int k = e >> 8, col0 = e & 255;
    const float4 w = *(const float4*)(W2 + k * HID + col0);
    const int s = k >> 5, lgw = (k >> 3) & 3, j = k & 7;
    #pragma unroll
    for (int q = 0; q < 4; ++q) {
        const float v = ((const float*)&w)[q];
        const int c = col0 + q, ct = c >> 4, cc = c & 15, l = (lgw << 4) | cc;
        w2p[(size_t)((s*16 + ct)*64 + l)*8 + j] = (f16)v;
    }
}

// LDS map (48896 B):
//   [0, 16384)      Bl0 (B chunk buffer, even chunks)
//   [16384, 32768)  Bl1 (odd chunks)
//   [32768, 45056)  W3s [256][12] f32
//   [45056, 46080)  b2s (256 f32)
//   [46080, 47104)  h1f (recompute scratch)
//   [47104, 48128)  h2f
//   [48128, 48896)  psum [12][16] (recompute)
__global__ __launch_bounds__(256, 2)
void mlp_main(const float* __restrict__ inp, const float* __restrict__ W1,
              const float* __restrict__ b1, const float* __restrict__ W2,
              const float* __restrict__ b2, const float* __restrict__ W3,
              const float* __restrict__ b3, const f16* __restrict__ w2p,
              float* __restrict__ out)
{
    __shared__ __align__(16) unsigned char smem[48896];
    __shared__ int nflag;
    __shared__ int flaglist[16];

    float* W3s  = (float*)(smem + 32768);
    float* b2s  = (float*)(smem + 45056);
    float* h1f  = (float*)(smem + 46080);
    float* h2f  = (float*)(smem + 47104);
    float* psum = (float*)(smem + 48128);

    const int t    = threadIdx.x;
    const int lane = t & 63;
    const int wid  = t >> 6;
    const int cl   = lane & 15;
    const int lg   = lane >> 4;
    const int row0 = blockIdx.x * BM;

    if (t == 0) nflag = 0;

    // ---- prologue: stage W3 (12 KB) + b2 (1 KB) + B chunk 0 (16 KB) ----
    {
        const char* w3c = (const char*)W3;
        #pragma unroll
        for (int i = 0; i < 3; ++i) {
            const int off = (wid*3 + i) * 1024;
            gll16(w3c + off + lane*16, smem + 32768 + off);
        }
        if (wid == 0) gll16((const char*)b2 + lane*16, smem + 45056);
        #pragma unroll
        for (int i = 0; i < 4; ++i)
            gll16((const char*)w2p + (i*256 + t)*16, smem + (i*256 + t)*16);
    }

    // ---- this lane's input row (A-frag: lane (cl,lg) owns row 16*wid+cl) ----
    const int myrow = row0 + wid*16 + cl;
    float xin[12];
    {
        const f32x4* ip = (const f32x4*)(inp + (size_t)myrow * NIN);
        const f32x4 a = ip[0], b = ip[1], c = ip[2];
        xin[0]=a.x; xin[1]=a.y; xin[2]=a.z; xin[3]=a.w;
        xin[4]=b.x; xin[5]=b.y; xin[6]=b.z; xin[7]=b.w;
        xin[8]=c.x; xin[9]=c.y; xin[10]=c.z; xin[11]=c.w;
    }

    // A-frag for chunk 0 (exact fp32 L1, then fp16 convert); covers chunk-0 load latency
    f16x8 aCur, aNxt;
    {
        const int k0 = 8*lg;
        float a0[8];
        const f32x4 bb0 = *(const f32x4*)(b1 + k0);
        const f32x4 bb1 = *(const f32x4*)(b1 + k0 + 4);
        a0[0]=bb0.x; a0[1]=bb0.y; a0[2]=bb0.z; a0[3]=bb0.w;
        a0[4]=bb1.x; a0[5]=bb1.y; a0[6]=bb1.z; a0[7]=bb1.w;
        #pragma unroll
        for (int m = 0; m < 12; ++m) {
            const float xm = xin[m];
            const f32x4 w0 = *(const f32x4*)(W1 + m*HID + k0);
            const f32x4 w1 = *(const f32x4*)(W1 + m*HID + k0 + 4);
            a0[0] = fmaf(xm, w0.x, a0[0]); a0[1] = fmaf(xm, w0.y, a0[1]);
            a0[2] = fmaf(xm, w0.z, a0[2]); a0[3] = fmaf(xm, w0.w, a0[3]);
            a0[4] = fmaf(xm, w1.x, a0[4]); a0[5] = fmaf(xm, w1.y, a0[5]);
            a0[6] = fmaf(xm, w1.z, a0[6]); a0[7] = fmaf(xm, w1.w, a0[7]);
        }
        #pragma unroll
        for (int j = 0; j < 8; ++j) aCur[j] = (f16)fmaxf(a0[j], 0.f);
    }
    asm volatile("s_waitcnt vmcnt(0)" ::: "memory");
    __syncthreads();

    // ---- GEMM2: single-product fp16 MFMA, double-buffered B, one barrier/chunk ----
    f32x4 acc[16];
    {
        const f32x4 zero = {0.f, 0.f, 0.f, 0.f};
        #pragma unroll
        for (int ct = 0; ct < 16; ++ct) acc[ct] = zero;
    }
    #pragma unroll
    for (int s = 0; s < 8; ++s) {
        // issue next chunk's staging into the other buffer (safe: barrier at end of
        // iteration s-1 guarantees everyone finished reading buf[(s+1)&1])
        if (s < 7) {
            const char* src = (const char*)w2p + (size_t)(s+1) * 16384;
            char* dst = (char*)smem + ((s+1)&1) * 16384;
            #pragma unroll
            for (int i = 0; i < 4; ++i)
                gll16(src + (i*256 + t)*16, dst + (i*256 + t)*16);
        }
        // MFMA on chunk s (loads for s+1 fly underneath)
        const char* bufr = (const char*)smem + (s&1) * 16384;
        #pragma unroll
        for (int ct = 0; ct < 16; ++ct) {
            const f16x8 bfrag = *(const f16x8*)(bufr + (size_t)(ct*64 + lane)*16);
            acc[ct] = __builtin_amdgcn_mfma_f32_16x16x32_f16(aCur, bfrag, acc[ct], 0, 0, 0);
        }
        // A-frag for chunk s+1 (VALU, also covers load latency)
        if (s < 7) {
            const int k0 = 32*(s+1) + 8*lg;
            float a0[8];
            const f32x4 bb0 = *(const f32x4*)(b1 + k0);
            const f32x4 bb1 = *(const f32x4*)(b1 + k0 + 4);
            a0[0]=bb0.x; a0[1]=bb0.y; a0[2]=bb0.z; a0[3]=bb0.w;
            a0[4]=bb1.x; a0[5]=bb1.y; a0[6]=bb1.z; a0[7]=bb1.w;
            #pragma unroll
            for (int m = 0; m < 12; ++m) {
                const float xm = xin[m];
                const f32x4 w0 = *(const f32x4*)(W1 + m*HID + k0);
                const f32x4 w1 = *(const f32x4*)(W1 + m*HID + k0 + 4);
                a0[0] = fmaf(xm, w0.x, a0[0]); a0[1] = fmaf(xm, w0.y, a0[1]);
                a0[2] = fmaf(xm, w0.z, a0[2]); a0[3] = fmaf(xm, w0.w, a0[3]);
                a0[4] = fmaf(xm, w1.x, a0[4]); a0[5] = fmaf(xm, w1.y, a0[5]);
                a0[6] = fmaf(xm, w1.z, a0[6]); a0[7] = fmaf(xm, w1.w, a0[7]);
            }
            #pragma unroll
            for (int j = 0; j < 8; ++j) aNxt[j] = (f16)fmaxf(a0[j], 0.f);
        }
        asm volatile("s_waitcnt vmcnt(0)" ::: "memory");
        __syncthreads();
        if (s < 7) aCur = aNxt;
    }

    // ---- Layer 3 (exact fp32), jj split 8/4 (b128 W3s reads), butterfly over cl ----
    float x[12];   // meaningful for cl<4 after butterflies
    {
        float part[4][8];
        #pragma unroll
        for (int q = 0; q < 4; ++q)
            #pragma unroll
            for (int jj = 0; jj < 8; ++jj) part[q][jj] = 0.f;

        #pragma unroll
        for (int ct = 0; ct < 16; ++ct) {
            const int col = ct*16 + cl;
            const float bv = b2s[col];
            const f32x4 w3a = *(const f32x4*)(W3s + col*12);
            const f32x4 w3b = *(const f32x4*)(W3s + col*12 + 4);
            #pragma unroll
            for (int q = 0; q < 4; ++q) {
                const float h2 = fmaxf(acc[ct][q] + bv, 0.f);
                part[q][0] = fmaf(h2, w3a.x, part[q][0]);
                part[q][1] = fmaf(h2, w3a.y, part[q][1]);
                part[q][2] = fmaf(h2, w3a.z, part[q][2]);
                part[q][3] = fmaf(h2, w3a.w, part[q][3]);
                part[q][4] = fmaf(h2, w3b.x, part[q][4]);
                part[q][5] = fmaf(h2, w3b.y, part[q][5]);
                part[q][6] = fmaf(h2, w3b.z, part[q][6]);
                part[q][7] = fmaf(h2, w3b.w, part[q][7]);
            }
        }
        #pragma unroll
        for (int m = 1; m < 16; m <<= 1)
            #pragma unroll
            for (int q = 0; q < 4; ++q)
                #pragma unroll
                for (int jj = 0; jj < 8; ++jj)
                    part[q][jj] += __shfl_xor(part[q][jj], m);
        if (cl < 4) {
            #pragma unroll
            for (int jj = 0; jj < 8; ++jj) x[jj] = part[cl][jj];
        }
    }
    {
        float part[4][4];
        #pragma unroll
        for (int q = 0; q < 4; ++q)
            #pragma unroll
            for (int jj = 0; jj < 4; ++jj) part[q][jj] = 0.f;

        #pragma unroll
        for (int ct = 0; ct < 16; ++ct) {
            const int col = ct*16 + cl;
            const float bv = b2s[col];
            const f32x4 w3c = *(const f32x4*)(W3s + col*12 + 8);
            #pragma unroll
            for (int q = 0; q < 4; ++q) {
                const float h2 = fmaxf(acc[ct][q] + bv, 0.f);
                part[q][0] = fmaf(h2, w3c.x, part[q][0]);
                part[q][1] = fmaf(h2, w3c.y, part[q][1]);
                part[q][2] = fmaf(h2, w3c.z, part[q][2]);
                part[q][3] = fmaf(h2, w3c.w, part[q][3]);
            }
        }
        #pragma unroll
        for (int m = 1; m < 16; m <<= 1)
            #pragma unroll
            for (int q = 0; q < 4; ++q)
                #pragma unroll
                for (int jj = 0; jj < 4; ++jj)
                    part[q][jj] += __shfl_xor(part[q][jj], m);
        if (cl < 4) {
            #pragma unroll
            for (int jj = 0; jj < 4; ++jj) x[8 + jj] = part[cl][jj];
        }
    }

    // ---- epilogue (exact fp32), lanes cl<4 each own row 16*wid + 4*lg + cl ----
    if (cl < 4) {
        const int R = wid*16 + 4*lg + cl;
        const int grow = row0 + R;
        #pragma unroll
        for (int jj = 0; jj < 12; ++jj) x[jj] += b3[jj];

        const f32x4* ip = (const f32x4*)(inp + (size_t)grow * NIN);
        const f32x4 iA = ip[0], iB = ip[1], iC = ip[2];
        const float in0=iA.x, in1=iA.y, in2=iA.z, in6=iB.z, in7=iB.w, in8=iC.x, in9=iC.y;

        const float pos0=tanhf(x[0]), pos1=tanhf(x[1]), pos2=tanhf(x[2]);
        const float vel0=tanhf(x[3]), vel1=tanhf(x[4]), vel2=tanhf(x[5]);
        const float pts = 1.f/(1.f+expf(-x[6]));
        const float cl0=tanhf(x[7]), cl1=tanhf(x[8]), cl2=tanhf(x[9]);
        const float sn0=tanhf(x[10]), sn1=tanhf(x[11]);

        const float dist = sqrtf(pos0*pos0 + pos1*pos1 + pos2*pos2);
        float pc0=pos0, pc1=pos1, pc2=pos2;
        if (dist > 1.0f) { pc0 = pos0/dist; pc1 = pos1/dist; pc2 = pos2/dist; }

        const float prev = in6;
        float pts_c = (pts > 1.0f) ? 1.0f : pts;
        pts_c = (pts < prev) ? prev : pts_c;

        const float de0 = cl0-in7, de1 = cl1-in8, de2 = cl2-in9;
        const float dp0 = in0-in7, dp1 = in1-in8, dp2 = in2-in9;
        const float dpn = sqrtf(dp0*dp0 + dp1*dp1 + dp2*dp2);
        const float nd0 = dp0/dpn, nd1 = dp1/dpn, nd2 = dp2/dpn;
        const float dd  = de0*dp0 + de1*dp1 + de2*dp2;
        float off0, off1, off2;
        if (dd > 0.0f) { off0 = cl0-nd0; off1 = cl1-nd1; off2 = cl2-nd2; }
        else           { off0 = cl0;     off1 = cl1;     off2 = cl2;     }
        const float cdist = sqrtf(off0*off0 + off1*off1 + off2*off2);
        float cc0, cc1, cc2;
        if (cdist > 1.0f) { cc0 = off0/cdist; cc1 = off1/cdist; cc2 = off2/cdist; }
        else              { cc0 = cl0;        cc1 = cl1;        cc2 = cl2;        }

        const float snn = sqrtf(sn0*sn0 + sn1*sn1);
        const float sc0 = sn0/snn, sc1 = sn1/snn;

        // guard: branch decisions within single-fp16 error margin -> exact recompute
        if (fabsf(dd) < 8e-3f || (dd > 0.f && fabsf(cdist - 1.f) < 4e-3f)) {
            const int slot = atomicAdd(&nflag, 1);
            if (slot < 16) flaglist[slot] = R;
        }

        f32x4* dst = (f32x4*)(out + (size_t)grow * NOUT);
        f32x4 o0 = {pc0, pc1, pc2, vel0};
        f32x4 o1 = {vel1, vel2, pts_c, cc0};
        f32x4 o2 = {cc1, cc2, sc0, sc1};
        dst[0] = o0; dst[1] = o1; dst[2] = o2;
    }
    __syncthreads();

    // ---- exact fp32 recompute of flagged rows (~1000 rows across whole GPU) ----
    const int nf = (nflag < 16) ? nflag : 16;
    for (int f = 0; f < nf; ++f) {
        const int grow = row0 + flaglist[f];
        {
            float a = b1[t];
            const float* xr = inp + (size_t)grow * NIN;
            #pragma unroll
            for (int m = 0; m < 12; ++m) a = fmaf(xr[m], W1[m*HID + t], a);
            h1f[t] = fmaxf(a, 0.f);
        }
        __syncthreads();
        {
            float a = b2[t];
            for (int k = 0; k < HID; ++k) a = fmaf(h1f[k], W2[k*HID + t], a);
            h2f[t] = fmaxf(a, 0.f);
        }
        __syncthreads();
        if (t < 12*16) {
            const int jj = t >> 4, seg = t & 15;
            float a = 0.f;
            #pragma unroll
            for (int u = 0; u < 16; ++u) a = fmaf(h2f[seg*16 + u], W3[(seg*16 + u)*NOUT + jj], a);
            psum[jj*16 + seg] = a;
        }
        __syncthreads();
        if (t == 0) {
            float xx[12];
            #pragma unroll
            for (int jj = 0; jj < 12; ++jj) {
                float sacc = b3[jj];
                for (int g = 0; g < 16; ++g) sacc += psum[jj*16 + g];
                xx[jj] = sacc;
            }
            const float* xr = inp + (size_t)grow * NIN;
            const float in0=xr[0], in1=xr[1], in2=xr[2], in6=xr[6], in7=xr[7], in8=xr[8], in9=xr[9];
            const float pos0=tanhf(xx[0]), pos1=tanhf(xx[1]), pos2=tanhf(xx[2]);
            const float vel0=tanhf(xx[3]), vel1=tanhf(xx[4]), vel2=tanhf(xx[5]);
            const float pts = 1.f/(1.f+expf(-xx[6]));
            const float cl0=tanhf(xx[7]), cl1=tanhf(xx[8]), cl2=tanhf(xx[9]);
            const float sn0=tanhf(xx[10]), sn1=tanhf(xx[11]);
            const float dist = sqrtf(pos0*pos0 + pos1*pos1 + pos2*pos2);
            float pc0=pos0, pc1=pos1, pc2=pos2;
            if (dist > 1.0f) { pc0 = pos0/dist; pc1 = pos1/dist; pc2 = pos2/dist; }
            const float prev = in6;
            float pts_c = (pts > 1.0f) ? 1.0f : pts;
            pts_c = (pts < prev) ? prev : pts_c;
            const float de0 = cl0-in7, de1 = cl1-in8, de2 = cl2-in9;
            const float dp0 = in0-in7, dp1 = in1-in8, dp2 = in2-in9;
            const float dpn = sqrtf(dp0*dp0 + dp1*dp1 + dp2*dp2);
            const float nd0 = dp0/dpn, nd1 = dp1/dpn, nd2 = dp2/dpn;
            const float dd  = de0*dp0 + de1*dp1 + de2*dp2;
            float off0, off1, off2;
            if (dd > 0.0f) { off0 = cl0-nd0; off1 = cl1-nd1; off2 = cl2-nd2; }
            else           { off0 = cl0;     off1 = cl1;     off2 = cl2;     }
            const float cdist = sqrtf(off0*off0 + off1*off1 + off2*off2);
            float cc0, cc1, cc2;
            if (cdist > 1.0f) { cc0 = off0/cdist; cc1 = off1/cdist; cc2 = off2/cdist; }
            else              { cc0 = cl0;        cc1 = cl1;        cc2 = cl2;        }
            const float snn = sqrtf(sn0*sn0 + sn1*sn1);
            const float sc0 = sn0/snn, sc1 = sn1/snn;
            float* dst = out + (size_t)grow * NOUT;
            dst[0]=pc0; dst[1]=pc1; dst[2]=pc2; dst[3]=vel0; dst[4]=vel1; dst[5]=vel2;
            dst[6]=pts_c; dst[7]=cc0; dst[8]=cc1; dst[9]=cc2; dst[10]=sc0; dst[11]=sc1;
        }
        __syncthreads();
    }
}

extern "C" void kernel_launch(void* const* d_in, const int* in_sizes, int n_in,
                              void* d_out, int out_size, void* d_ws, size_t ws_size,
                              hipStream_t stream) {
    const float* inp = (const float*)d_in[0];
    const float* W1  = (const float*)d_in[1];
    const float* b1  = (const float*)d_in[2];
    const float* W2  = (const float*)d_in[3];
    const float* b2  = (const float*)d_in[4];
    const float* W3  = (const float*)d_in[5];
    const float* b3  = (const float*)d_in[6];
    float* out = (float*)d_out;
    f16* w2p = (f16*)d_ws;   // needs 128 KB

    hipLaunchKernelGGL(prep_w2, dim3(64), dim3(256), 0, stream, W2, w2p);
    hipLaunchKernelGGL(mlp_main, dim3(NBLK), dim3(256), 0, stream,
                       inp, W1, b1, W2, b2, W3, b3, (const f16*)w2p, out);
}

// Round 10
// 236.597 us; speedup vs baseline: 1.5655x; 1.2150x over previous
//
#include <hip/hip_runtime.h>
#include <math.h>

#define NIN 12
#define HID 256
#define NOUT 12
#define BM 64
#define NBLK (262144 / BM)

typedef _Float16 f16;
typedef f16 f16x8 __attribute__((ext_vector_type(8)));
typedef float f32x4 __attribute__((ext_vector_type(4)));

__device__ __forceinline__ void gll16(const void* g, void* l) {
    __builtin_amdgcn_global_load_lds(
        (const __attribute__((address_space(1))) unsigned int*)g,
        (__attribute__((address_space(3))) unsigned int*)l, 16, 0, 0);
}

// d_ws: W2 fp16 splits in MFMA-B fragment order:
// half index = (((s*2 + spl)*16 + ct)*64 + l)*8 + j
// where k = 32s + 8*(l>>4) + j, col = 16*ct + (l&15). Total 131072 halfs = 256 KB.
__global__ void prep_w2(const float* __restrict__ W2, f16* __restrict__ w2p) {
    const int e = (blockIdx.x * 256 + threadIdx.x) * 4;
    const int k = e >> 8, col0 = e & 255;
    const float4 w = *(const float4*)(W2 + k * HID + col0);
    const int s = k >> 5, lgw = (k >> 3) & 3, j = k & 7;
    #pragma unroll
    for (int q = 0; q < 4; ++q) {
        const float v = ((const float*)&w)[q];
        const f16 hi = (f16)v;
        const f16 lo = (f16)(v - (float)hi);
        const int c = col0 + q, ct = c >> 4, cc = c & 15, l = (lgw << 4) | cc;
        w2p[(size_t)(((s*2 + 0)*16 + ct)*64 + l)*8 + j] = hi;
        w2p[(size_t)(((s*2 + 1)*16 + ct)*64 + l)*8 + j] = lo;
    }
}

// LDS map (69376 B):
//   [0, 32768)      Bl0 (even chunks); post-GEMM overlay: W3s [0,12288)
//   [32768, 65536)  Bl1 (odd chunks)
//   [65536, 66560)  b2s (256 f32)
//   [66560, 67584)  h1f (recompute scratch)
//   [67584, 68608)  h2f
//   [68608, 69376)  psum [12][16] (recompute)
__global__ __launch_bounds__(256, 2)
void mlp_main(const float* __restrict__ inp, const float* __restrict__ W1,
              const float* __restrict__ b1, const float* __restrict__ W2,
              const float* __restrict__ b2, const float* __restrict__ W3,
              const float* __restrict__ b3, const f16* __restrict__ w2p,
              float* __restrict__ out)
{
    __shared__ __align__(16) unsigned char smem[69376];
    __shared__ int nflag;
    __shared__ int flaglist[16];

    float* W3s  = (float*)smem;               // valid only after the GEMM loop
    float* b2s  = (float*)(smem + 65536);
    float* h1f  = (float*)(smem + 66560);
    float* h2f  = (float*)(smem + 67584);
    float* psum = (float*)(smem + 68608);

    const int t    = threadIdx.x;
    const int lane = t & 63;
    const int wid  = t >> 6;
    const int cl   = lane & 15;
    const int lg   = lane >> 4;
    const int row0 = blockIdx.x * BM;

    if (t == 0) nflag = 0;

    // ---- prologue: stage b2 (1 KB) + B chunk 0 (32 KB into Bl0) ----
    {
        if (wid == 0) gll16((const char*)b2 + lane*16, smem + 65536);
        #pragma unroll
        for (int i = 0; i < 8; ++i) {
            const int off = (i*4 + wid) * 1024;
            gll16((const char*)w2p + off + lane*16, smem + off);
        }
    }

    // ---- this lane's input row (A-frag: lane (cl,lg) owns row 16*wid+cl) ----
    const int myrow = row0 + wid*16 + cl;
    float xin[12];
    {
        const f32x4* ip = (const f32x4*)(inp + (size_t)myrow * NIN);
        const f32x4 a = ip[0], b = ip[1], c = ip[2];
        xin[0]=a.x; xin[1]=a.y; xin[2]=a.z; xin[3]=a.w;
        xin[4]=b.x; xin[5]=b.y; xin[6]=b.z; xin[7]=b.w;
        xin[8]=c.x; xin[9]=c.y; xin[10]=c.z; xin[11]=c.w;
    }

    // ---- GEMM2: dbuf B staging, counted vmcnt, 3-product split-fp16 MFMA ----
    f32x4 acc[16];
    {
        const f32x4 zero = {0.f, 0.f, 0.f, 0.f};
        #pragma unroll
        for (int ct = 0; ct < 16; ++ct) acc[ct] = zero;
    }
    #pragma unroll
    for (int s = 0; s < 8; ++s) {
        // issue prefetch of chunk s+1 into the other buffer.
        // Safe: the post-MFMA barrier of iteration s-1 guaranteed all waves
        // finished reading buf[(s+1)&1] (which held chunk s-1).
        if (s < 7) {
            const char* src = (const char*)w2p + (size_t)(s+1) * 32768;
            char* dst = (char*)smem + ((s+1)&1) * 32768;
            #pragma unroll
            for (int i = 0; i < 8; ++i) {
                const int off = (i*4 + wid) * 1024;
                gll16(src + off + lane*16, dst + off);
            }
        }
        // Layer 1 A-frag for chunk s (register-only after L1-resident W1 loads)
        const int k0 = 32*s + 8*lg;
        float a0[8];
        {
            const f32x4 bb0 = *(const f32x4*)(b1 + k0);
            const f32x4 bb1 = *(const f32x4*)(b1 + k0 + 4);
            a0[0]=bb0.x; a0[1]=bb0.y; a0[2]=bb0.z; a0[3]=bb0.w;
            a0[4]=bb1.x; a0[5]=bb1.y; a0[6]=bb1.z; a0[7]=bb1.w;
        }
        #pragma unroll
        for (int m = 0; m < 12; ++m) {
            const float xm = xin[m];
            const f32x4 w0 = *(const f32x4*)(W1 + m*HID + k0);
            const f32x4 w1 = *(const f32x4*)(W1 + m*HID + k0 + 4);
            a0[0] = fmaf(xm, w0.x, a0[0]); a0[1] = fmaf(xm, w0.y, a0[1]);
            a0[2] = fmaf(xm, w0.z, a0[2]); a0[3] = fmaf(xm, w0.w, a0[3]);
            a0[4] = fmaf(xm, w1.x, a0[4]); a0[5] = fmaf(xm, w1.y, a0[5]);
            a0[6] = fmaf(xm, w1.z, a0[6]); a0[7] = fmaf(xm, w1.w, a0[7]);
        }
        f16x8 ahi, alo;
        #pragma unroll
        for (int j = 0; j < 8; ++j) {
            const float h = fmaxf(a0[j], 0.f);
            const f16 hi = (f16)h;
            ahi[j] = hi;
            alo[j] = (f16)(h - (float)hi);
        }
        // counted wait: chunk-s staging (issued a full iteration ago) must have
        // landed; the 8 in-flight prefetch loads of chunk s+1 are NOT waited on.
        if (s < 7) { asm volatile("s_waitcnt vmcnt(8)" ::: "memory"); }
        else       { asm volatile("s_waitcnt vmcnt(0)" ::: "memory"); }
        __syncthreads();   // chunk-s writes from all waves visible

        const char* bufr = (const char*)smem + (s&1) * 32768;
        #pragma unroll
        for (int ct = 0; ct < 16; ++ct) {
            const f16x8 bhi = *(const f16x8*)(bufr + (size_t)(( 0 + ct)*64 + lane)*16);
            const f16x8 blo = *(const f16x8*)(bufr + (size_t)((16 + ct)*64 + lane)*16);
            acc[ct] = __builtin_amdgcn_mfma_f32_16x16x32_f16(ahi, bhi, acc[ct], 0, 0, 0);
            acc[ct] = __builtin_amdgcn_mfma_f32_16x16x32_f16(ahi, blo, acc[ct], 0, 0, 0);
            acc[ct] = __builtin_amdgcn_mfma_f32_16x16x32_f16(alo, bhi, acc[ct], 0, 0, 0);
        }
        __syncthreads();   // all waves done reading buf[s&1]; next iter may restage it
    }

    // ---- stage W3 into the (dead) Bl0 region ----
    {
        const char* w3c = (const char*)W3;
        #pragma unroll
        for (int i = 0; i < 3; ++i) {
            const int off = (wid*3 + i) * 1024;
            gll16(w3c + off + lane*16, smem + off);
        }
    }
    asm volatile("s_waitcnt vmcnt(0)" ::: "memory");
    __syncthreads();

    // ---- Layer 3 (exact fp32), jj split 8/4 (b128 W3s reads), butterfly over cl ----
    float x[12];   // meaningful for cl<4 after butterflies
    {
        float part[4][8];
        #pragma unroll
        for (int q = 0; q < 4; ++q)
            #pragma unroll
            for (int jj = 0; jj < 8; ++jj) part[q][jj] = 0.f;

        #pragma unroll
        for (int ct = 0; ct < 16; ++ct) {
            const int col = ct*16 + cl;
            const float bv = b2s[col];
            const f32x4 w3a = *(const f32x4*)(W3s + col*12);
            const f32x4 w3b = *(const f32x4*)(W3s + col*12 + 4);
            #pragma unroll
            for (int q = 0; q < 4; ++q) {
                const float h2 = fmaxf(acc[ct][q] + bv, 0.f);
                part[q][0] = fmaf(h2, w3a.x, part[q][0]);
                part[q][1] = fmaf(h2, w3a.y, part[q][1]);
                part[q][2] = fmaf(h2, w3a.z, part[q][2]);
                part[q][3] = fmaf(h2, w3a.w, part[q][3]);
                part[q][4] = fmaf(h2, w3b.x, part[q][4]);
                part[q][5] = fmaf(h2, w3b.y, part[q][5]);
                part[q][6] = fmaf(h2, w3b.z, part[q][6]);
                part[q][7] = fmaf(h2, w3b.w, part[q][7]);
            }
        }
        #pragma unroll
        for (int m = 1; m < 16; m <<= 1)
            #pragma unroll
            for (int q = 0; q < 4; ++q)
                #pragma unroll
                for (int jj = 0; jj < 8; ++jj)
                    part[q][jj] += __shfl_xor(part[q][jj], m);
        if (cl < 4) {
            #pragma unroll
            for (int jj = 0; jj < 8; ++jj) x[jj] = part[cl][jj];
        }
    }
    {
        float part[4][4];
        #pragma unroll
        for (int q = 0; q < 4; ++q)
            #pragma unroll
            for (int jj = 0; jj < 4; ++jj) part[q][jj] = 0.f;

        #pragma unroll
        for (int ct = 0; ct < 16; ++ct) {
            const int col = ct*16 + cl;
            const float bv = b2s[col];
            const f32x4 w3c = *(const f32x4*)(W3s + col*12 + 8);
            #pragma unroll
            for (int q = 0; q < 4; ++q) {
                const float h2 = fmaxf(acc[ct][q] + bv, 0.f);
                part[q][0] = fmaf(h2, w3c.x, part[q][0]);
                part[q][1] = fmaf(h2, w3c.y, part[q][1]);
                part[q][2] = fmaf(h2, w3c.z, part[q][2]);
                part[q][3] = fmaf(h2, w3c.w, part[q][3]);
            }
        }
        #pragma unroll
        for (int m = 1; m < 16; m <<= 1)
            #pragma unroll
            for (int q = 0; q < 4; ++q)
                #pragma unroll
                for (int jj = 0; jj < 4; ++jj)
                    part[q][jj] += __shfl_xor(part[q][jj], m);
        if (cl < 4) {
            #pragma unroll
            for (int jj = 0; jj < 4; ++jj) x[8 + jj] = part[cl][jj];
        }
    }

    // ---- epilogue (exact fp32), lanes cl<4 each own row 16*wid + 4*lg + cl ----
    if (cl < 4) {
        const int R = wid*16 + 4*lg + cl;
        const int grow = row0 + R;
        #pragma unroll
        for (int jj = 0; jj < 12; ++jj) x[jj] += b3[jj];

        const f32x4* ip = (const f32x4*)(inp + (size_t)grow * NIN);
        const f32x4 iA = ip[0], iB = ip[1], iC = ip[2];
        const float in0=iA.x, in1=iA.y, in2=iA.z, in6=iB.z, in7=iB.w, in8=iC.x, in9=iC.y;

        const float pos0=tanhf(x[0]), pos1=tanhf(x[1]), pos2=tanhf(x[2]);
        const float vel0=tanhf(x[3]), vel1=tanhf(x[4]), vel2=tanhf(x[5]);
        const float pts = 1.f/(1.f+expf(-x[6]));
        const float cl0=tanhf(x[7]), cl1=tanhf(x[8]), cl2=tanhf(x[9]);
        const float sn0=tanhf(x[10]), sn1=tanhf(x[11]);

        const float dist = sqrtf(pos0*pos0 + pos1*pos1 + pos2*pos2);
        float pc0=pos0, pc1=pos1, pc2=pos2;
        if (dist > 1.0f) { pc0 = pos0/dist; pc1 = pos1/dist; pc2 = pos2/dist; }

        const float prev = in6;
        float pts_c = (pts > 1.0f) ? 1.0f : pts;
        pts_c = (pts < prev) ? prev : pts_c;

        const float de0 = cl0-in7, de1 = cl1-in8, de2 = cl2-in9;
        const float dp0 = in0-in7, dp1 = in1-in8, dp2 = in2-in9;
        const float dpn = sqrtf(dp0*dp0 + dp1*dp1 + dp2*dp2);
        const float nd0 = dp0/dpn, nd1 = dp1/dpn, nd2 = dp2/dpn;
        const float dd  = de0*dp0 + de1*dp1 + de2*dp2;
        float off0, off1, off2;
        if (dd > 0.0f) { off0 = cl0-nd0; off1 = cl1-nd1; off2 = cl2-nd2; }
        else           { off0 = cl0;     off1 = cl1;     off2 = cl2;     }
        const float cdist = sqrtf(off0*off0 + off1*off1 + off2*off2);
        float cc0, cc1, cc2;
        if (cdist > 1.0f) { cc0 = off0/cdist; cc1 = off1/cdist; cc2 = off2/cdist; }
        else              { cc0 = cl0;        cc1 = cl1;        cc2 = cl2;        }

        const float snn = sqrtf(sn0*sn0 + sn1*sn1);
        const float sc0 = sn0/snn, sc1 = sn1/snn;

        // guard: branch decisions within fp16-split error margin -> exact recompute
        if (fabsf(dd) < 2e-4f || (dd > 0.f && fabsf(cdist - 1.f) < 2e-4f)) {
            const int slot = atomicAdd(&nflag, 1);
            if (slot < 16) flaglist[slot] = R;
        }

        f32x4* dst = (f32x4*)(out + (size_t)grow * NOUT);
        f32x4 o0 = {pc0, pc1, pc2, vel0};
        f32x4 o1 = {vel1, vel2, pts_c, cc0};
        f32x4 o2 = {cc1, cc2, sc0, sc1};
        dst[0] = o0; dst[1] = o1; dst[2] = o2;
    }
    __syncthreads();

    // ---- exact fp32 recompute of flagged rows (rare across whole GPU) ----
    const int nf = (nflag < 16) ? nflag : 16;
    for (int f = 0; f < nf; ++f) {
        const int grow = row0 + flaglist[f];
        {
            float a = b1[t];
            const float* xr = inp + (size_t)grow * NIN;
            #pragma unroll
            for (int m = 0; m < 12; ++m) a = fmaf(xr[m], W1[m*HID + t], a);
            h1f[t] = fmaxf(a, 0.f);
        }
        __syncthreads();
        {
            float a = b2[t];
            for (int k = 0; k < HID; ++k) a = fmaf(h1f[k], W2[k*HID + t], a);
            h2f[t] = fmaxf(a, 0.f);
        }
        __syncthreads();
        if (t < 12*16) {
            const int jj = t >> 4, seg = t & 15;
            float a = 0.f;
            #pragma unroll
            for (int u = 0; u < 16; ++u) a = fmaf(h2f[seg*16 + u], W3[(seg*16 + u)*NOUT + jj], a);
            psum[jj*16 + seg] = a;
        }
        __syncthreads();
        if (t == 0) {
            float xx[12];
            #pragma unroll
            for (int jj = 0; jj < 12; ++jj) {
                float sacc = b3[jj];
                for (int g = 0; g < 16; ++g) sacc += psum[jj*16 + g];
                xx[jj] = sacc;
            }
            const float* xr = inp + (size_t)grow * NIN;
            const float in0=xr[0], in1=xr[1], in2=xr[2], in6=xr[6], in7=xr[7], in8=xr[8], in9=xr[9];
            const float pos0=tanhf(xx[0]), pos1=tanhf(xx[1]), pos2=tanhf(xx[2]);
            const float vel0=tanhf(xx[3]), vel1=tanhf(xx[4]), vel2=tanhf(xx[5]);
            const float pts = 1.f/(1.f+expf(-xx[6]));
            const float cl0=tanhf(xx[7]), cl1=tanhf(xx[8]), cl2=tanhf(xx[9]);
            const float sn0=tanhf(xx[10]), sn1=tanhf(xx[11]);
            const float dist = sqrtf(pos0*pos0 + pos1*pos1 + pos2*pos2);
            float pc0=pos0, pc1=pos1, pc2=pos2;
            if (dist > 1.0f) { pc0 = pos0/dist; pc1 = pos1/dist; pc2 = pos2/dist; }
            const float prev = in6;
            float pts_c = (pts > 1.0f) ? 1.0f : pts;
            pts_c = (pts < prev) ? prev : pts_c;
            const float de0 = cl0-in7, de1 = cl1-in8, de2 = cl2-in9;
            const float dp0 = in0-in7, dp1 = in1-in8, dp2 = in2-in9;
            const float dpn = sqrtf(dp0*dp0 + dp1*dp1 + dp2*dp2);
            const float nd0 = dp0/dpn, nd1 = dp1/dpn, nd2 = dp2/dpn;
            const float dd  = de0*dp0 + de1*dp1 + de2*dp2;
            float off0, off1, off2;
            if (dd > 0.0f) { off0 = cl0-nd0; off1 = cl1-nd1; off2 = cl2-nd2; }
            else           { off0 = cl0;     off1 = cl1;     off2 = cl2;     }
            const float cdist = sqrtf(off0*off0 + off1*off1 + off2*off2);
            float cc0, cc1, cc2;
            if (cdist > 1.0f) { cc0 = off0/cdist; cc1 = off1/cdist; cc2 = off2/cdist; }
            else              { cc0 = cl0;        cc1 = cl1;        cc2 = cl2;        }
            const float snn = sqrtf(sn0*sn0 + sn1*sn1);
            const float sc0 = sn0/snn, sc1 = sn1/snn;
            float* dst = out + (size_t)grow * NOUT;
            dst[0]=pc0; dst[1]=pc1; dst[2]=pc2; dst[3]=vel0; dst[4]=vel1; dst[5]=vel2;
            dst[6]=pts_c; dst[7]=cc0; dst[8]=cc1; dst[9]=cc2; dst[10]=sc0; dst[11]=sc1;
        }
        __syncthreads();
    }
}

extern "C" void kernel_launch(void* const* d_in, const int* in_sizes, int n_in,
                              void* d_out, int out_size, void* d_ws, size_t ws_size,
                              hipStream_t stream) {
    const float* inp = (const float*)d_in[0];
    const float* W1  = (const float*)d_in[1];
    const float* b1  = (const float*)d_in[2];
    const float* W2  = (const float*)d_in[3];
    const float* b2  = (const float*)d_in[4];
    const float* W3  = (const float*)d_in[5];
    const float* b3  = (const float*)d_in[6];
    float* out = (float*)d_out;
    f16* w2p = (f16*)d_ws;   // needs 256 KB

    hipLaunchKernelGGL(prep_w2, dim3(64), dim3(256), 0, stream, W2, w2p);
    hipLaunchKernelGGL(mlp_main, dim3(NBLK), dim3(256), 0, stream,
                       inp, W1, b1, W2, b2, W3, b3, (const f16*)w2p, out);
}